// Round 1
// baseline (821.200 us; speedup 1.0000x reference)
//
#include <hip/hip_runtime.h>

// ---------------------------------------------------------------------------
// SpatialGraphConv: N=32,C=32,V=400,L=64; 2 graphs, order 2, K=20, alpha=.05
// out = BN( sum_k M_k * (S_k x) ),  S in {I, A0^T, (A0^T)^2, A1^T, (A1^T)^2}
// ---------------------------------------------------------------------------

#define VDIM 400
#define VP   416            // v padded to multiple of 32
#define KV   (4*VP)         // 1664 : concat K dim over k=1..4
#define EROWS (5*VP)        // 2080 : e rows incl k=0
#define OL   2048           // 32 out-ch * 64 l
#define ALPHA_ 0.05f
#define BETA_  0.95f

typedef short  bf16x8 __attribute__((ext_vector_type(8)));
typedef float  f32x4  __attribute__((ext_vector_type(4)));

__device__ inline unsigned short f2bf(float x){
  unsigned int u = __float_as_uint(x);
  unsigned int r = (u + 0x7fffu + ((u >> 16) & 1u)) >> 16;
  return (unsigned short)r;
}
__device__ inline float bf2f(unsigned short u){
  return __uint_as_float(((unsigned int)u) << 16);
}

// ---------------------------------------------------------------- edge MLP --
__global__ __launch_bounds__(256) void k_mlp(
    const float* __restrict__ adj,
    const float* __restrict__ w0, const float* __restrict__ b0,
    const float* __restrict__ w1, const float* __restrict__ b1,
    const float* __restrict__ w2, const float* __restrict__ b2,
    float* __restrict__ g)
{
  __shared__ __align__(16) float s_in[32*64];
  __shared__ __align__(16) float s_w [8192];
  __shared__ __align__(16) float s_h0[32*128];
  __shared__ __align__(16) float s_h1[32*64];
  const int tid = threadIdx.x;
  const long ebase = (long)blockIdx.x * 32;

  { const float4* src = reinterpret_cast<const float4*>(adj + ebase*64);
    float4* dst = reinterpret_cast<float4*>(s_in);
    for (int i = tid; i < 512; i += 256) dst[i] = src[i];
    const float4* ws_ = reinterpret_cast<const float4*>(w0);
    float4* wd = reinterpret_cast<float4*>(s_w);
    for (int i = tid; i < 2048; i += 256) wd[i] = ws_[i]; }
  __syncthreads();
  { const int eg = tid >> 5, og = tid & 31;
    float acc[4][4];
    #pragma unroll
    for (int j = 0; j < 4; ++j){ float bb = b0[og*4+j];
      #pragma unroll
      for (int i = 0; i < 4; ++i) acc[i][j] = bb; }
    for (int f = 0; f < 64; ++f){
      float a0 = s_in[(eg*4+0)*64+f], a1 = s_in[(eg*4+1)*64+f];
      float a2 = s_in[(eg*4+2)*64+f], a3 = s_in[(eg*4+3)*64+f];
      float4 bb = *reinterpret_cast<const float4*>(&s_w[f*128 + og*4]);
      acc[0][0]+=a0*bb.x; acc[0][1]+=a0*bb.y; acc[0][2]+=a0*bb.z; acc[0][3]+=a0*bb.w;
      acc[1][0]+=a1*bb.x; acc[1][1]+=a1*bb.y; acc[1][2]+=a1*bb.z; acc[1][3]+=a1*bb.w;
      acc[2][0]+=a2*bb.x; acc[2][1]+=a2*bb.y; acc[2][2]+=a2*bb.z; acc[2][3]+=a2*bb.w;
      acc[3][0]+=a3*bb.x; acc[3][1]+=a3*bb.y; acc[3][2]+=a3*bb.z; acc[3][3]+=a3*bb.w;
    }
    #pragma unroll
    for (int i = 0; i < 4; ++i)
      #pragma unroll
      for (int j = 0; j < 4; ++j)
        s_h0[(eg*4+i)*128 + og*4 + j] = fmaxf(acc[i][j], 0.f);
  }
  __syncthreads();
  { const float4* ws_ = reinterpret_cast<const float4*>(w1);
    float4* wd = reinterpret_cast<float4*>(s_w);
    for (int i = tid; i < 2048; i += 256) wd[i] = ws_[i]; }
  __syncthreads();
  { const int e = tid >> 3, ug = tid & 7;
    float acc[8];
    #pragma unroll
    for (int j = 0; j < 8; ++j) acc[j] = b1[ug*8+j];
    for (int f = 0; f < 128; ++f){
      float a = s_h0[e*128 + f];
      float4 q0 = *reinterpret_cast<const float4*>(&s_w[f*64 + ug*8]);
      float4 q1 = *reinterpret_cast<const float4*>(&s_w[f*64 + ug*8 + 4]);
      acc[0]+=a*q0.x; acc[1]+=a*q0.y; acc[2]+=a*q0.z; acc[3]+=a*q0.w;
      acc[4]+=a*q1.x; acc[5]+=a*q1.y; acc[6]+=a*q1.z; acc[7]+=a*q1.w;
    }
    #pragma unroll
    for (int j = 0; j < 8; ++j) s_h1[e*64 + ug*8 + j] = fmaxf(acc[j], 0.f);
  }
  __syncthreads();
  if (tid < 64){
    const int e = tid >> 1, gr = tid & 1;
    float acc = b2[gr];
    for (int u = 0; u < 64; ++u) acc += s_h1[e*64+u] * w2[u*2+gr];
    g[(ebase + e)*2 + gr] = acc;
  }
}

// ------------------------------------------- softmax + top-K + renorm + ^T --
// writes Bf[gr*2][w][v] = A_gr[v][w]   (1-hop transposed operator, fp32)
__global__ __launch_bounds__(256) void k_sparsify(
    const float* __restrict__ g, float* __restrict__ Bf)
{
  const int row = blockIdx.x, gr = blockIdx.y, tid = threadIdx.x;
  const int wid = tid >> 6, lane = tid & 63;
  __shared__ float s_v[4]; __shared__ int s_i[4];
  __shared__ float s_p[512];
  __shared__ int   s_sel[512];
  const int i0 = tid, i1 = tid + 256;
  float v0 = (i0 < VDIM) ? g[(row*VDIM + i0)*2 + gr] : -3.4e38f;
  float v1 = (i1 < VDIM) ? g[(row*VDIM + i1)*2 + gr] : -3.4e38f;

  float m = fmaxf(v0, v1);
  for (int off = 32; off > 0; off >>= 1) m = fmaxf(m, __shfl_down(m, off, 64));
  if (lane == 0) s_v[wid] = m;
  __syncthreads();
  const float rowmax = fmaxf(fmaxf(s_v[0], s_v[1]), fmaxf(s_v[2], s_v[3]));
  float p0 = (i0 < VDIM) ? expf(v0 - rowmax) : 0.f;
  float p1 = (i1 < VDIM) ? expf(v1 - rowmax) : 0.f;
  float zs = p0 + p1;
  for (int off = 32; off > 0; off >>= 1) zs += __shfl_down(zs, off, 64);
  __syncthreads();
  if (lane == 0) s_v[wid] = zs;
  __syncthreads();
  const float Z = s_v[0] + s_v[1] + s_v[2] + s_v[3];
  p0 /= Z; p1 /= Z;
  s_p[i0] = p0; s_p[i1] = p1;
  s_sel[i0] = (i0 < VDIM) ? 0 : 1;
  s_sel[i1] = (i1 < VDIM) ? 0 : 1;
  __syncthreads();

  float ssum = 0.f;
  for (int it = 0; it < 20; ++it){
    float cv = -1.f; int ci = 0x7fffffff;
    if (!s_sel[i0])              { cv = p0; ci = i0; }
    if (!s_sel[i1] && (p1 > cv)) { cv = p1; ci = i1; }
    for (int off = 32; off > 0; off >>= 1){
      float ov = __shfl_down(cv, off, 64); int oi = __shfl_down(ci, off, 64);
      if (ov > cv || (ov == cv && oi < ci)){ cv = ov; ci = oi; }
    }
    if (lane == 0){ s_v[wid] = cv; s_i[wid] = ci; }
    __syncthreads();
    float wv = s_v[0]; int wi_ = s_i[0];
    #pragma unroll
    for (int k = 1; k < 4; ++k){
      float ov = s_v[k]; int oi = s_i[k];
      if (ov > wv || (ov == wv && oi < wi_)){ wv = ov; wi_ = oi; }
    }
    ssum += wv;
    if (tid == (wi_ & 255)) s_sel[wi_] = 1;
    __syncthreads();
  }
  const float inv = 1.0f / (ssum + 1e-8f);
  float* B1 = Bf + (size_t)(gr*2) * (VDIM*VDIM);
  if (i0 < VDIM) B1[(size_t)i0*VDIM + row] = s_sel[i0] ? (s_p[i0]*inv) : 0.f;
  if (i1 < VDIM) B1[(size_t)i1*VDIM + row] = s_sel[i1] ? (s_p[i1]*inv) : 0.f;
}

// ------------------------------------------------ 2-hop: Bf[2g+1]=Bf[2g]^2 --
__global__ __launch_bounds__(256) void k_sq(float* __restrict__ Bf)
{
  const int gr = blockIdx.z;
  const float* S = Bf + (size_t)(2*gr)   * (VDIM*VDIM);
  float*       D = Bf + (size_t)(2*gr+1) * (VDIM*VDIM);
  const int tx = threadIdx.x & 15, ty = threadIdx.x >> 4;
  const int w = blockIdx.x*16 + ty, v = blockIdx.y*16 + tx;
  __shared__ float As[16][17], Bs[16][17];
  float acc = 0.f;
  for (int u0 = 0; u0 < VDIM; u0 += 16){
    As[ty][tx] = S[(size_t)w*VDIM + u0 + tx];
    Bs[ty][tx] = S[(size_t)(u0+ty)*VDIM + v];
    __syncthreads();
    #pragma unroll
    for (int u = 0; u < 16; ++u) acc += As[ty][u] * Bs[u][tx];
    __syncthreads();
  }
  D[(size_t)w*VDIM + v] = acc;
}

// ------------------- pack Bcat (bf16, padded) + build M'' + zero BN sums ---
__global__ __launch_bounds__(256) void k_pack(
    const float* __restrict__ Bf, const float* __restrict__ conv_w,
    unsigned short* __restrict__ Bcat, unsigned short* __restrict__ Mpp,
    float* __restrict__ bns)
{
  const int idx = blockIdx.x*256 + threadIdx.x;
  if (idx < 512*KV){
    const int w = idx / KV, col = idx % KV;
    const int k1 = col / VP, v = col % VP;
    float val = (w < VDIM && v < VDIM) ? Bf[(size_t)k1*(VDIM*VDIM) + (size_t)w*VDIM + v] : 0.f;
    Bcat[idx] = f2bf(val);
  }
  if (blockIdx.x == 0){
    const float a = ALPHA_, b = BETA_;
    for (int mIdx = threadIdx.x; mIdx < 160*32; mIdx += 256){
      const int rowm = mIdx >> 5, c = mIdx & 31;
      const int k = rowm / 32, o = rowm & 31;
      float W[5];
      #pragma unroll
      for (int j = 0; j < 5; ++j) W[j] = conv_w[o*160 + j*32 + c];
      float val;
      if      (k == 0) val = W[0] + a*(W[1]+W[2]+W[3]+W[4]);
      else if (k == 1) val = b*W[1] + a*b*W[2];
      else if (k == 2) val = b*b*W[2];
      else if (k == 3) val = b*W[3] + a*b*W[4];
      else             val = b*b*W[4];
      Mpp[rowm*32 + c] = f2bf(val);
    }
    if (threadIdx.x < 64) bns[threadIdx.x] = 0.f;
  }
}

// ----------------- e_k = M_k * relu(x), bf16, layout [n'][k*416+v][o*64+l] --
__global__ __launch_bounds__(640) void k_e(
    const float* __restrict__ x, const unsigned short* __restrict__ Mpp,
    unsigned short* __restrict__ e, int n0)
{
  const int v = blockIdx.x;
  const int n = n0 + blockIdx.y;
  const int tid = threadIdx.x;
  unsigned short* en = e + (size_t)blockIdx.y * EROWS * OL;
  if (v >= VDIM){
    for (int i = tid; i < 5*256; i += 640){
      const int k = i >> 8, off = (i & 255) * 8;
      *reinterpret_cast<uint4*>(&en[(size_t)(k*VP + v)*OL + off]) = make_uint4(0,0,0,0);
    }
    return;
  }
  __shared__ __align__(16) unsigned short s_xT[64*32];      // [l][c]
  __shared__ __align__(16) unsigned short s_out[10*16*64];  // per-wave [16][64]
  if (tid < 512){
    const int c = tid >> 4, l4 = (tid & 15) * 4;
    float4 xv = *reinterpret_cast<const float4*>(x + ((size_t)n*32 + c)*25600 + (size_t)v*64 + l4);
    s_xT[(l4+0)*32 + c] = f2bf(fmaxf(xv.x, 0.f));
    s_xT[(l4+1)*32 + c] = f2bf(fmaxf(xv.y, 0.f));
    s_xT[(l4+2)*32 + c] = f2bf(fmaxf(xv.z, 0.f));
    s_xT[(l4+3)*32 + c] = f2bf(fmaxf(xv.w, 0.f));
  }
  __syncthreads();
  const int wid = tid >> 6, lane = tid & 63;
  const int l15 = lane & 15, q = lane >> 4;
  const int m0 = wid * 16;
  bf16x8 afrag = *reinterpret_cast<const bf16x8*>(&Mpp[(m0 + l15)*32 + q*8]);
  const f32x4 zero = {0.f, 0.f, 0.f, 0.f};
  f32x4 acc[4];
  #pragma unroll
  for (int lt = 0; lt < 4; ++lt){
    bf16x8 bfrag = *reinterpret_cast<const bf16x8*>(&s_xT[(lt*16 + l15)*32 + q*8]);
    acc[lt] = __builtin_amdgcn_mfma_f32_16x16x32_bf16(afrag, bfrag, zero, 0, 0, 0);
  }
  unsigned short* so = &s_out[wid*1024];
  #pragma unroll
  for (int lt = 0; lt < 4; ++lt)
    #pragma unroll
    for (int r = 0; r < 4; ++r)
      so[(q*4 + r)*64 + lt*16 + l15] = f2bf(acc[lt][r]);
  const int k = wid >> 1, o0 = (wid & 1) * 16;
  const size_t gbase = (size_t)(k*VP + v)*OL + (size_t)o0*64;
  uint4 d0 = *reinterpret_cast<uint4*>(&so[lane*16]);
  uint4 d1 = *reinterpret_cast<uint4*>(&so[lane*16 + 8]);
  *reinterpret_cast<uint4*>(&en[gbase + lane*16])     = d0;
  *reinterpret_cast<uint4*>(&en[gbase + lane*16 + 8]) = d1;
}

// ------- main GEMM: out[w][(o,l)] = Bcat[w][kv] @ e[kv][(o,l)] + e0 + bias --
__global__ __launch_bounds__(256) void k_prop(
    const unsigned short* __restrict__ Bcat, const unsigned short* __restrict__ e,
    const float* __restrict__ conv_b, float* __restrict__ out,
    float* __restrict__ bns, int n0)
{
  const int mt = blockIdx.x, nt = blockIdx.y, np = blockIdx.z;
  const int tid = threadIdx.x;
  const int wid = tid >> 6, lane = tid & 63;
  const int l15 = lane & 15, q = lane >> 4;
  const int ww = wid & 1, wh = wid >> 1;
  const unsigned short* en = e + (size_t)np * EROWS * OL;
  __shared__ __align__(16) unsigned short s_a[128*40];  // padded rows
  __shared__ __align__(16) unsigned short s_b[128*32];  // xor-swizzled [n][k]
  const f32x4 zero = {0.f, 0.f, 0.f, 0.f};
  f32x4 acc[4][4];
  #pragma unroll
  for (int mi = 0; mi < 4; ++mi)
    #pragma unroll
    for (int ni = 0; ni < 4; ++ni) acc[mi][ni] = zero;
  const int w_base = mt*128, ol0 = nt*128;

  for (int kk = 0; kk < KV; kk += 32){
    #pragma unroll
    for (int i = 0; i < 2; ++i){
      const int idx = tid + i*256;
      const int m = idx >> 2, seg = idx & 3;
      uint4 d = *reinterpret_cast<const uint4*>(&Bcat[(size_t)(w_base + m)*KV + kk + seg*8]);
      *reinterpret_cast<uint4*>(&s_a[m*40 + seg*8]) = d;
    }
    #pragma unroll
    for (int i = 0; i < 2; ++i){
      const int idx = tid + i*256;
      const int r = idx >> 4, seg = idx & 15;
      union { uint4 u; unsigned short s[8]; } d;
      d.u = *reinterpret_cast<const uint4*>(&en[(size_t)(VP + kk + r)*OL + ol0 + seg*8]);
      const int kb = r >> 3, kin = r & 7;
      #pragma unroll
      for (int t = 0; t < 8; ++t){
        const int nn = seg*8 + t;
        s_b[nn*32 + ((kb ^ ((nn >> 3) & 3)) << 3) + kin] = d.s[t];
      }
    }
    __syncthreads();
    bf16x8 af[4], bfr[4];
    #pragma unroll
    for (int mi = 0; mi < 4; ++mi){
      const int m = ww*64 + mi*16 + l15;
      af[mi] = *reinterpret_cast<const bf16x8*>(&s_a[m*40 + q*8]);
    }
    #pragma unroll
    for (int ni = 0; ni < 4; ++ni){
      const int nn = wh*64 + ni*16 + l15;
      bfr[ni] = *reinterpret_cast<const bf16x8*>(&s_b[nn*32 + ((q ^ ((nn >> 3) & 3)) << 3)]);
    }
    #pragma unroll
    for (int mi = 0; mi < 4; ++mi)
      #pragma unroll
      for (int ni = 0; ni < 4; ++ni)
        acc[mi][ni] = __builtin_amdgcn_mfma_f32_16x16x32_bf16(af[mi], bfr[ni], acc[mi][ni], 0, 0, 0);
    __syncthreads();
  }

  const int n_g = n0 + np;
  const int o = (ol0 >> 6) + wh;          // each wave maps to exactly one out channel
  const float cb = conv_b[o];
  float bsum = 0.f, bsq = 0.f;
  #pragma unroll
  for (int mi = 0; mi < 4; ++mi){
    #pragma unroll
    for (int ni = 0; ni < 4; ++ni){
      const int nloc = wh*64 + ni*16 + l15;
      const int ol = ol0 + nloc;
      const int l = ol & 63;
      #pragma unroll
      for (int r = 0; r < 4; ++r){
        const int w = w_base + ww*64 + mi*16 + q*4 + r;
        if (w < VDIM){
          float val = acc[mi][ni][r] + bf2f(en[(size_t)w*OL + ol]) + cb;
          out[(((size_t)n_g*32 + o)*VDIM + w)*64 + l] = val;
          bsum += val; bsq += val*val;
        }
      }
    }
  }
  for (int off = 32; off > 0; off >>= 1){
    bsum += __shfl_down(bsum, off, 64);
    bsq  += __shfl_down(bsq,  off, 64);
  }
  if (lane == 0){
    atomicAdd(&bns[o], bsum);
    atomicAdd(&bns[32 + o], bsq);
  }
}

// --------------------------------------------------- batchnorm (in-place) --
__global__ __launch_bounds__(256) void k_bnapply(
    float* __restrict__ out, const float* __restrict__ bns,
    const float* __restrict__ gamma, const float* __restrict__ beta, int total4)
{
  const int idx = blockIdx.x*256 + threadIdx.x;
  if (idx >= total4) return;
  const int o = (int)(((long)idx*4 / 25600) & 31);
  const float invM = 1.f / 819200.f;
  const float mean = bns[o] * invM;
  const float var  = bns[32+o] * invM - mean*mean;
  const float inv  = 1.0f / sqrtf(var + 1e-5f);
  const float sc = inv * gamma[o];
  const float sh = beta[o] - mean * sc;
  float4 v = reinterpret_cast<float4*>(out)[idx];
  v.x = v.x*sc + sh; v.y = v.y*sc + sh; v.z = v.z*sc + sh; v.w = v.w*sc + sh;
  reinterpret_cast<float4*>(out)[idx] = v;
}

// ---------------------------------------------------------------------------
extern "C" void kernel_launch(void* const* d_in, const int* in_sizes, int n_in,
                              void* d_out, int out_size, void* d_ws, size_t ws_size,
                              hipStream_t stream)
{
  const float* x      = (const float*)d_in[0];
  const float* adj    = (const float*)d_in[1];
  const float* w0     = (const float*)d_in[2];
  const float* b0     = (const float*)d_in[3];
  const float* w1     = (const float*)d_in[4];
  const float* b1     = (const float*)d_in[5];
  const float* w2     = (const float*)d_in[6];
  const float* b2     = (const float*)d_in[7];
  const float* conv_w = (const float*)d_in[8];
  const float* conv_b = (const float*)d_in[9];
  const float* gamma  = (const float*)d_in[10];
  const float* beta   = (const float*)d_in[11];
  float* out = (float*)d_out;

  char* ws = (char*)d_ws;
  size_t off = 0;
  auto alloc = [&](size_t bytes) -> void* {
    void* p = ws + off;
    off = (off + bytes + 255) & ~(size_t)255;
    return p;
  };
  float*          g_   = (float*)         alloc((size_t)VDIM*VDIM*2*4);
  float*          Bf   = (float*)         alloc((size_t)4*VDIM*VDIM*4);
  unsigned short* Bcat = (unsigned short*)alloc((size_t)512*KV*2);
  unsigned short* Mpp  = (unsigned short*)alloc((size_t)160*32*2);
  float*          bns  = (float*)         alloc((size_t)64*4);
  const size_t per_n = (size_t)EROWS * OL * 2;
  size_t avail = (ws_size > off) ? (ws_size - off) : 0;
  int NC = (int)(avail / per_n);
  if (NC > 8) NC = 8;
  if (NC < 1) NC = 1;
  while (32 % NC) NC--;
  unsigned short* ebuf = (unsigned short*)(ws + off);

  k_mlp<<<5000, 256, 0, stream>>>(adj, w0, b0, w1, b1, w2, b2, g_);
  k_sparsify<<<dim3(VDIM, 2), 256, 0, stream>>>(g_, Bf);
  k_sq<<<dim3(25, 25, 2), 256, 0, stream>>>(Bf);
  k_pack<<<(512*KV + 255)/256, 256, 0, stream>>>(Bf, conv_w, Bcat, Mpp, bns);
  for (int n0 = 0; n0 < 32; n0 += NC){
    k_e<<<dim3(VP, NC), 640, 0, stream>>>(x, Mpp, ebuf, n0);
    k_prop<<<dim3(4, 16, NC), 256, 0, stream>>>(Bcat, ebuf, conv_b, out, bns, n0);
  }
  k_bnapply<<<(26214400/4 + 255)/256, 256, 0, stream>>>(out, bns, gamma, beta, 26214400/4);
}

// Round 3
// 784.197 us; speedup vs baseline: 1.0472x; 1.0472x over previous
//
#include <hip/hip_runtime.h>

// ---------------------------------------------------------------------------
// SpatialGraphConv: N=32,C=32,V=400,L=64; 2 graphs, order 2, K=20, alpha=.05
// out = BN( sum_k M_k * (S_k x) ),  S in {I, A0^T, (A0^T)^2, A1^T, (A1^T)^2}
// MLP kept fp32 (logit noise must be <1e-3: softmax probs feed out linearly;
// bf16 MLP measured 0.59 absmax in R2). Main GEMM path bf16 MFMA (verified).
// ---------------------------------------------------------------------------

#define VDIM 400
#define VP   416            // v padded to multiple of 32
#define KV   (4*VP)         // 1664 : concat K dim over k=1..4
#define EROWS (5*VP)        // 2080 : e rows incl k=0
#define OL   2048           // 32 out-ch * 64 l
#define ALPHA_ 0.05f
#define BETA_  0.95f

typedef short  bf16x8 __attribute__((ext_vector_type(8)));
typedef float  f32x4  __attribute__((ext_vector_type(4)));

__device__ inline unsigned short f2bf(float x){
  unsigned int u = __float_as_uint(x);
  unsigned int r = (u + 0x7fffu + ((u >> 16) & 1u)) >> 16;
  return (unsigned short)r;
}
__device__ inline float bf2f(unsigned short u){
  return __uint_as_float(((unsigned int)u) << 16);
}

// ------------------------------------------------- edge MLP, fp32, tuned ---
// 64 edges/block, 256 threads. eg=tid>>4 (4 edges each), ng=tid&15 (4 cols).
// LDS strides: s_in 68, s_h0 132, s_w 64 -> all access patterns <=2-way.
__global__ __launch_bounds__(256) void k_mlp3(
    const float* __restrict__ adj,
    const float* __restrict__ w0, const float* __restrict__ b0,
    const float* __restrict__ w1, const float* __restrict__ b1,
    const float* __restrict__ w2, const float* __restrict__ b2,
    float* __restrict__ g)
{
  __shared__ __align__(16) float s_in[64*68];   // 17,408 B
  __shared__ __align__(16) float s_h0[64*132];  // 33,792 B
  __shared__ __align__(16) float s_w [64*64];   // 16,384 B
  const int tid = threadIdx.x;
  const long ebase = (long)blockIdx.x * 64;
  const int eg = tid >> 4;          // 0..15 -> edges eg*4..+3
  const int ng = tid & 15;          // 0..15 -> cols ng*4..+3

  // stage adj tile [64][64] (pad 68)
  #pragma unroll
  for (int i = 0; i < 4; ++i){
    const int idx = tid + i*256;
    const int row = idx >> 4, f4 = (idx & 15)*4;
    *reinterpret_cast<f32x4*>(&s_in[row*68 + f4]) =
      *reinterpret_cast<const f32x4*>(&adj[(ebase + row)*64 + f4]);
  }
  // stage w0 n-half 0: s_w[f][nn] = w0[f][nn]
  #pragma unroll
  for (int i = 0; i < 4; ++i){
    const int idx = tid + i*256;
    const int f = idx >> 4, nn = (idx & 15)*4;
    *reinterpret_cast<f32x4*>(&s_w[f*64 + nn]) =
      *reinterpret_cast<const f32x4*>(&w0[f*128 + nn]);
  }
  __syncthreads();

  const f32x4 b0h0 = *reinterpret_cast<const f32x4*>(&b0[ng*4]);
  const f32x4 b0h1 = *reinterpret_cast<const f32x4*>(&b0[64 + ng*4]);
  const f32x4 b1v  = *reinterpret_cast<const f32x4*>(&b1[ng*4]);
  const f32x4 w2lo = *reinterpret_cast<const f32x4*>(&w2[ng*8]);
  const f32x4 w2hi = *reinterpret_cast<const f32x4*>(&w2[ng*8 + 4]);

  // ---- layer 0: h0[64e][128n], K=64, in two n-halves
  #pragma unroll
  for (int h = 0; h < 2; ++h){
    if (h == 1){
      __syncthreads();   // all reads of s_w half0 done
      #pragma unroll
      for (int i = 0; i < 4; ++i){
        const int idx = tid + i*256;
        const int f = idx >> 4, nn = (idx & 15)*4;
        *reinterpret_cast<f32x4*>(&s_w[f*64 + nn]) =
          *reinterpret_cast<const f32x4*>(&w0[f*128 + 64 + nn]);
      }
      __syncthreads();
    }
    f32x4 acc[4];
    #pragma unroll
    for (int i = 0; i < 4; ++i) acc[i] = (f32x4){0.f,0.f,0.f,0.f};
    for (int f4 = 0; f4 < 64; f4 += 4){
      f32x4 wv0 = *reinterpret_cast<const f32x4*>(&s_w[(f4+0)*64 + ng*4]);
      f32x4 wv1 = *reinterpret_cast<const f32x4*>(&s_w[(f4+1)*64 + ng*4]);
      f32x4 wv2 = *reinterpret_cast<const f32x4*>(&s_w[(f4+2)*64 + ng*4]);
      f32x4 wv3 = *reinterpret_cast<const f32x4*>(&s_w[(f4+3)*64 + ng*4]);
      #pragma unroll
      for (int i = 0; i < 4; ++i){
        f32x4 av = *reinterpret_cast<const f32x4*>(&s_in[(eg*4+i)*68 + f4]);
        acc[i] += av.x*wv0 + av.y*wv1 + av.z*wv2 + av.w*wv3;
      }
    }
    const f32x4 bb = h ? b0h1 : b0h0;
    #pragma unroll
    for (int i = 0; i < 4; ++i){
      f32x4 v = acc[i] + bb;
      v.x = fmaxf(v.x, 0.f); v.y = fmaxf(v.y, 0.f);
      v.z = fmaxf(v.z, 0.f); v.w = fmaxf(v.w, 0.f);
      *reinterpret_cast<f32x4*>(&s_h0[(eg*4+i)*132 + h*64 + ng*4]) = v;
    }
  }
  __syncthreads();   // h0 visible; s_w free

  // ---- layer 1: h1[64e][64n], K=128, in two f-halves (acc in regs)
  f32x4 acc1[4];
  #pragma unroll
  for (int i = 0; i < 4; ++i) acc1[i] = (f32x4){0.f,0.f,0.f,0.f};
  #pragma unroll
  for (int h = 0; h < 2; ++h){
    #pragma unroll
    for (int i = 0; i < 4; ++i){
      const int idx = tid + i*256;
      const int fr = idx >> 4, nn = (idx & 15)*4;
      *reinterpret_cast<f32x4*>(&s_w[fr*64 + nn]) =
        *reinterpret_cast<const f32x4*>(&w1[(h*64 + fr)*64 + nn]);
    }
    __syncthreads();
    for (int f4 = 0; f4 < 64; f4 += 4){
      f32x4 wv0 = *reinterpret_cast<const f32x4*>(&s_w[(f4+0)*64 + ng*4]);
      f32x4 wv1 = *reinterpret_cast<const f32x4*>(&s_w[(f4+1)*64 + ng*4]);
      f32x4 wv2 = *reinterpret_cast<const f32x4*>(&s_w[(f4+2)*64 + ng*4]);
      f32x4 wv3 = *reinterpret_cast<const f32x4*>(&s_w[(f4+3)*64 + ng*4]);
      #pragma unroll
      for (int i = 0; i < 4; ++i){
        f32x4 av = *reinterpret_cast<const f32x4*>(&s_h0[(eg*4+i)*132 + h*64 + f4]);
        acc1[i] += av.x*wv0 + av.y*wv1 + av.z*wv2 + av.w*wv3;
      }
    }
    __syncthreads();   // before restage / done
  }

  // ---- layer 2: g[e][gr] = h1[e][:] @ w2 + b2 ; reduce over ng lanes
  float p0[4], p1[4];
  #pragma unroll
  for (int i = 0; i < 4; ++i){
    f32x4 hv = acc1[i] + b1v;
    hv.x = fmaxf(hv.x, 0.f); hv.y = fmaxf(hv.y, 0.f);
    hv.z = fmaxf(hv.z, 0.f); hv.w = fmaxf(hv.w, 0.f);
    p0[i] = hv.x*w2lo.x + hv.y*w2lo.z + hv.z*w2hi.x + hv.w*w2hi.z;
    p1[i] = hv.x*w2lo.y + hv.y*w2lo.w + hv.z*w2hi.y + hv.w*w2hi.w;
  }
  #pragma unroll
  for (int m = 8; m >= 1; m >>= 1){
    #pragma unroll
    for (int i = 0; i < 4; ++i){
      p0[i] += __shfl_xor(p0[i], m, 16);
      p1[i] += __shfl_xor(p1[i], m, 16);
    }
  }
  if (ng == 0){
    const float bb0 = b2[0], bb1 = b2[1];
    #pragma unroll
    for (int i = 0; i < 4; ++i){
      const long e = ebase + eg*4 + i;
      g[e*2 + 0] = p0[i] + bb0;
      g[e*2 + 1] = p1[i] + bb1;
    }
  }
}

// ------------------------------------------- softmax + top-K + renorm + ^T --
// writes Bf[gr*2][w][v] = A_gr[v][w]   (1-hop transposed operator, fp32)
__global__ __launch_bounds__(256) void k_sparsify(
    const float* __restrict__ g, float* __restrict__ Bf)
{
  const int row = blockIdx.x, gr = blockIdx.y, tid = threadIdx.x;
  const int wid = tid >> 6, lane = tid & 63;
  __shared__ float s_v[4]; __shared__ int s_i[4];
  __shared__ float s_p[512];
  __shared__ int   s_sel[512];
  const int i0 = tid, i1 = tid + 256;
  float v0 = (i0 < VDIM) ? g[(row*VDIM + i0)*2 + gr] : -3.4e38f;
  float v1 = (i1 < VDIM) ? g[(row*VDIM + i1)*2 + gr] : -3.4e38f;

  float m = fmaxf(v0, v1);
  for (int off = 32; off > 0; off >>= 1) m = fmaxf(m, __shfl_down(m, off, 64));
  if (lane == 0) s_v[wid] = m;
  __syncthreads();
  const float rowmax = fmaxf(fmaxf(s_v[0], s_v[1]), fmaxf(s_v[2], s_v[3]));
  float p0 = (i0 < VDIM) ? expf(v0 - rowmax) : 0.f;
  float p1 = (i1 < VDIM) ? expf(v1 - rowmax) : 0.f;
  float zs = p0 + p1;
  for (int off = 32; off > 0; off >>= 1) zs += __shfl_down(zs, off, 64);
  __syncthreads();
  if (lane == 0) s_v[wid] = zs;
  __syncthreads();
  const float Z = s_v[0] + s_v[1] + s_v[2] + s_v[3];
  p0 /= Z; p1 /= Z;
  s_p[i0] = p0; s_p[i1] = p1;
  s_sel[i0] = (i0 < VDIM) ? 0 : 1;
  s_sel[i1] = (i1 < VDIM) ? 0 : 1;
  __syncthreads();

  float ssum = 0.f;
  for (int it = 0; it < 20; ++it){
    float cv = -1.f; int ci = 0x7fffffff;
    if (!s_sel[i0])              { cv = p0; ci = i0; }
    if (!s_sel[i1] && (p1 > cv)) { cv = p1; ci = i1; }
    for (int off = 32; off > 0; off >>= 1){
      float ov = __shfl_down(cv, off, 64); int oi = __shfl_down(ci, off, 64);
      if (ov > cv || (ov == cv && oi < ci)){ cv = ov; ci = oi; }
    }
    if (lane == 0){ s_v[wid] = cv; s_i[wid] = ci; }
    __syncthreads();
    float wv = s_v[0]; int wi_ = s_i[0];
    #pragma unroll
    for (int k = 1; k < 4; ++k){
      float ov = s_v[k]; int oi = s_i[k];
      if (ov > wv || (ov == wv && oi < wi_)){ wv = ov; wi_ = oi; }
    }
    ssum += wv;
    if (tid == (wi_ & 255)) s_sel[wi_] = 1;
    __syncthreads();
  }
  const float inv = 1.0f / (ssum + 1e-8f);
  float* B1 = Bf + (size_t)(gr*2) * (VDIM*VDIM);
  if (i0 < VDIM) B1[(size_t)i0*VDIM + row] = s_sel[i0] ? (s_p[i0]*inv) : 0.f;
  if (i1 < VDIM) B1[(size_t)i1*VDIM + row] = s_sel[i1] ? (s_p[i1]*inv) : 0.f;
}

// ------------------------------------------------ 2-hop: Bf[2g+1]=Bf[2g]^2 --
__global__ __launch_bounds__(256) void k_sq(float* __restrict__ Bf)
{
  const int gr = blockIdx.z;
  const float* S = Bf + (size_t)(2*gr)   * (VDIM*VDIM);
  float*       D = Bf + (size_t)(2*gr+1) * (VDIM*VDIM);
  const int tx = threadIdx.x & 15, ty = threadIdx.x >> 4;
  const int w = blockIdx.x*16 + ty, v = blockIdx.y*16 + tx;
  __shared__ float As[16][17], Bs[16][17];
  float acc = 0.f;
  for (int u0 = 0; u0 < VDIM; u0 += 16){
    As[ty][tx] = S[(size_t)w*VDIM + u0 + tx];
    Bs[ty][tx] = S[(size_t)(u0+ty)*VDIM + v];
    __syncthreads();
    #pragma unroll
    for (int u = 0; u < 16; ++u) acc += As[ty][u] * Bs[u][tx];
    __syncthreads();
  }
  D[(size_t)w*VDIM + v] = acc;
}

// ------------------- pack Bcat (bf16, padded) + build M'' + zero BN sums ---
__global__ __launch_bounds__(256) void k_pack(
    const float* __restrict__ Bf, const float* __restrict__ conv_w,
    unsigned short* __restrict__ Bcat, unsigned short* __restrict__ Mpp,
    float* __restrict__ bns)
{
  const int idx = blockIdx.x*256 + threadIdx.x;
  if (idx < 512*KV){
    const int w = idx / KV, col = idx % KV;
    const int k1 = col / VP, v = col % VP;
    float val = (w < VDIM && v < VDIM) ? Bf[(size_t)k1*(VDIM*VDIM) + (size_t)w*VDIM + v] : 0.f;
    Bcat[idx] = f2bf(val);
  }
  if (blockIdx.x == 0){
    const float a = ALPHA_, b = BETA_;
    for (int mIdx = threadIdx.x; mIdx < 160*32; mIdx += 256){
      const int rowm = mIdx >> 5, c = mIdx & 31;
      const int k = rowm / 32, o = rowm & 31;
      float W[5];
      #pragma unroll
      for (int j = 0; j < 5; ++j) W[j] = conv_w[o*160 + j*32 + c];
      float val;
      if      (k == 0) val = W[0] + a*(W[1]+W[2]+W[3]+W[4]);
      else if (k == 1) val = b*W[1] + a*b*W[2];
      else if (k == 2) val = b*b*W[2];
      else if (k == 3) val = b*W[3] + a*b*W[4];
      else             val = b*b*W[4];
      Mpp[rowm*32 + c] = f2bf(val);
    }
    if (threadIdx.x < 64) bns[threadIdx.x] = 0.f;
  }
}

// ----------------- e_k = M_k * relu(x), bf16, layout [n'][k*416+v][o*64+l] --
__global__ __launch_bounds__(640) void k_e(
    const float* __restrict__ x, const unsigned short* __restrict__ Mpp,
    unsigned short* __restrict__ e, int n0)
{
  const int v = blockIdx.x;
  const int n = n0 + blockIdx.y;
  const int tid = threadIdx.x;
  unsigned short* en = e + (size_t)blockIdx.y * EROWS * OL;
  if (v >= VDIM){
    for (int i = tid; i < 5*256; i += 640){
      const int k = i >> 8, off = (i & 255) * 8;
      *reinterpret_cast<uint4*>(&en[(size_t)(k*VP + v)*OL + off]) = make_uint4(0,0,0,0);
    }
    return;
  }
  __shared__ __align__(16) unsigned short s_xT[64*32];      // [l][c]
  __shared__ __align__(16) unsigned short s_out[10*16*64];  // per-wave [16][64]
  if (tid < 512){
    const int c = tid >> 4, l4 = (tid & 15) * 4;
    float4 xv = *reinterpret_cast<const float4*>(x + ((size_t)n*32 + c)*25600 + (size_t)v*64 + l4);
    s_xT[(l4+0)*32 + c] = f2bf(fmaxf(xv.x, 0.f));
    s_xT[(l4+1)*32 + c] = f2bf(fmaxf(xv.y, 0.f));
    s_xT[(l4+2)*32 + c] = f2bf(fmaxf(xv.z, 0.f));
    s_xT[(l4+3)*32 + c] = f2bf(fmaxf(xv.w, 0.f));
  }
  __syncthreads();
  const int wid = tid >> 6, lane = tid & 63;
  const int l15 = lane & 15, q = lane >> 4;
  const int m0 = wid * 16;
  bf16x8 afrag = *reinterpret_cast<const bf16x8*>(&Mpp[(m0 + l15)*32 + q*8]);
  const f32x4 zero = {0.f, 0.f, 0.f, 0.f};
  f32x4 acc[4];
  #pragma unroll
  for (int lt = 0; lt < 4; ++lt){
    bf16x8 bfrag = *reinterpret_cast<const bf16x8*>(&s_xT[(lt*16 + l15)*32 + q*8]);
    acc[lt] = __builtin_amdgcn_mfma_f32_16x16x32_bf16(afrag, bfrag, zero, 0, 0, 0);
  }
  unsigned short* so = &s_out[wid*1024];
  #pragma unroll
  for (int lt = 0; lt < 4; ++lt)
    #pragma unroll
    for (int r = 0; r < 4; ++r)
      so[(q*4 + r)*64 + lt*16 + l15] = f2bf(acc[lt][r]);
  const int k = wid >> 1, o0 = (wid & 1) * 16;
  const size_t gbase = (size_t)(k*VP + v)*OL + (size_t)o0*64;
  uint4 d0 = *reinterpret_cast<uint4*>(&so[lane*16]);
  uint4 d1 = *reinterpret_cast<uint4*>(&so[lane*16 + 8]);
  *reinterpret_cast<uint4*>(&en[gbase + lane*16])     = d0;
  *reinterpret_cast<uint4*>(&en[gbase + lane*16 + 8]) = d1;
}

// ------- main GEMM: out[w][(o,l)] = Bcat[w][kv] @ e[kv][(o,l)] + e0 + bias --
__global__ __launch_bounds__(256) void k_prop(
    const unsigned short* __restrict__ Bcat, const unsigned short* __restrict__ e,
    const float* __restrict__ conv_b, float* __restrict__ out,
    float* __restrict__ bns, int n0)
{
  const int mt = blockIdx.x, nt = blockIdx.y, np = blockIdx.z;
  const int tid = threadIdx.x;
  const int wid = tid >> 6, lane = tid & 63;
  const int l15 = lane & 15, q = lane >> 4;
  const int ww = wid & 1, wh = wid >> 1;
  const unsigned short* en = e + (size_t)np * EROWS * OL;
  __shared__ __align__(16) unsigned short s_a[128*40];  // padded rows
  __shared__ __align__(16) unsigned short s_b[128*32];  // xor-swizzled [n][k]
  const f32x4 zero = {0.f, 0.f, 0.f, 0.f};
  f32x4 acc[4][4];
  #pragma unroll
  for (int mi = 0; mi < 4; ++mi)
    #pragma unroll
    for (int ni = 0; ni < 4; ++ni) acc[mi][ni] = zero;
  const int w_base = mt*128, ol0 = nt*128;

  for (int kk = 0; kk < KV; kk += 32){
    #pragma unroll
    for (int i = 0; i < 2; ++i){
      const int idx = tid + i*256;
      const int m = idx >> 2, seg = idx & 3;
      uint4 d = *reinterpret_cast<const uint4*>(&Bcat[(size_t)(w_base + m)*KV + kk + seg*8]);
      *reinterpret_cast<uint4*>(&s_a[m*40 + seg*8]) = d;
    }
    #pragma unroll
    for (int i = 0; i < 2; ++i){
      const int idx = tid + i*256;
      const int r = idx >> 4, seg = idx & 15;
      union { uint4 u; unsigned short s[8]; } d;
      d.u = *reinterpret_cast<const uint4*>(&en[(size_t)(VP + kk + r)*OL + ol0 + seg*8]);
      const int kb = r >> 3, kin = r & 7;
      #pragma unroll
      for (int t = 0; t < 8; ++t){
        const int nn = seg*8 + t;
        s_b[nn*32 + ((kb ^ ((nn >> 3) & 3)) << 3) + kin] = d.s[t];
      }
    }
    __syncthreads();
    bf16x8 af[4], bfr[4];
    #pragma unroll
    for (int mi = 0; mi < 4; ++mi){
      const int m = ww*64 + mi*16 + l15;
      af[mi] = *reinterpret_cast<const bf16x8*>(&s_a[m*40 + q*8]);
    }
    #pragma unroll
    for (int ni = 0; ni < 4; ++ni){
      const int nn = wh*64 + ni*16 + l15;
      bfr[ni] = *reinterpret_cast<const bf16x8*>(&s_b[nn*32 + ((q ^ ((nn >> 3) & 3)) << 3)]);
    }
    #pragma unroll
    for (int mi = 0; mi < 4; ++mi)
      #pragma unroll
      for (int ni = 0; ni < 4; ++ni)
        acc[mi][ni] = __builtin_amdgcn_mfma_f32_16x16x32_bf16(af[mi], bfr[ni], acc[mi][ni], 0, 0, 0);
    __syncthreads();
  }

  const int n_g = n0 + np;
  const int o = (ol0 >> 6) + wh;          // each wave maps to exactly one out channel
  const float cb = conv_b[o];
  float bsum = 0.f, bsq = 0.f;
  #pragma unroll
  for (int mi = 0; mi < 4; ++mi){
    #pragma unroll
    for (int ni = 0; ni < 4; ++ni){
      const int nloc = wh*64 + ni*16 + l15;
      const int ol = ol0 + nloc;
      const int l = ol & 63;
      #pragma unroll
      for (int r = 0; r < 4; ++r){
        const int w = w_base + ww*64 + mi*16 + q*4 + r;
        if (w < VDIM){
          float val = acc[mi][ni][r] + bf2f(en[(size_t)w*OL + ol]) + cb;
          out[(((size_t)n_g*32 + o)*VDIM + w)*64 + l] = val;
          bsum += val; bsq += val*val;
        }
      }
    }
  }
  for (int off = 32; off > 0; off >>= 1){
    bsum += __shfl_down(bsum, off, 64);
    bsq  += __shfl_down(bsq,  off, 64);
  }
  if (lane == 0){
    atomicAdd(&bns[o], bsum);
    atomicAdd(&bns[32 + o], bsq);
  }
}

// --------------------------------------------------- batchnorm (in-place) --
__global__ __launch_bounds__(256) void k_bnapply(
    float* __restrict__ out, const float* __restrict__ bns,
    const float* __restrict__ gamma, const float* __restrict__ beta, int total4)
{
  const int idx = blockIdx.x*256 + threadIdx.x;
  if (idx >= total4) return;
  const int o = (int)(((long)idx*4 / 25600) & 31);
  const float invM = 1.f / 819200.f;
  const float mean = bns[o] * invM;
  const float var  = bns[32+o] * invM - mean*mean;
  const float inv  = 1.0f / sqrtf(var + 1e-5f);
  const float sc = inv * gamma[o];
  const float sh = beta[o] - mean * sc;
  float4 v = reinterpret_cast<float4*>(out)[idx];
  v.x = v.x*sc + sh; v.y = v.y*sc + sh; v.z = v.z*sc + sh; v.w = v.w*sc + sh;
  reinterpret_cast<float4*>(out)[idx] = v;
}

// ---------------------------------------------------------------------------
extern "C" void kernel_launch(void* const* d_in, const int* in_sizes, int n_in,
                              void* d_out, int out_size, void* d_ws, size_t ws_size,
                              hipStream_t stream)
{
  const float* x      = (const float*)d_in[0];
  const float* adj    = (const float*)d_in[1];
  const float* w0     = (const float*)d_in[2];
  const float* b0     = (const float*)d_in[3];
  const float* w1     = (const float*)d_in[4];
  const float* b1     = (const float*)d_in[5];
  const float* w2     = (const float*)d_in[6];
  const float* b2     = (const float*)d_in[7];
  const float* conv_w = (const float*)d_in[8];
  const float* conv_b = (const float*)d_in[9];
  const float* gamma  = (const float*)d_in[10];
  const float* beta   = (const float*)d_in[11];
  float* out = (float*)d_out;

  char* ws = (char*)d_ws;
  size_t off = 0;
  auto alloc = [&](size_t bytes) -> void* {
    void* p = ws + off;
    off = (off + bytes + 255) & ~(size_t)255;
    return p;
  };
  float*          g_   = (float*)         alloc((size_t)VDIM*VDIM*2*4);
  float*          Bf   = (float*)         alloc((size_t)4*VDIM*VDIM*4);
  unsigned short* Bcat = (unsigned short*)alloc((size_t)512*KV*2);
  unsigned short* Mpp  = (unsigned short*)alloc((size_t)160*32*2);
  float*          bns  = (float*)         alloc((size_t)64*4);
  const size_t per_n = (size_t)EROWS * OL * 2;
  size_t avail = (ws_size > off) ? (ws_size - off) : 0;
  int NC = (int)(avail / per_n);
  if (NC > 8) NC = 8;
  if (NC < 1) NC = 1;
  while (32 % NC) NC--;
  unsigned short* ebuf = (unsigned short*)(ws + off);

  k_mlp3<<<2500, 256, 0, stream>>>(adj, w0, b0, w1, b1, w2, b2, g_);
  k_sparsify<<<dim3(VDIM, 2), 256, 0, stream>>>(g_, Bf);
  k_sq<<<dim3(25, 25, 2), 256, 0, stream>>>(Bf);
  k_pack<<<(512*KV + 255)/256, 256, 0, stream>>>(Bf, conv_w, Bcat, Mpp, bns);
  for (int n0 = 0; n0 < 32; n0 += NC){
    k_e<<<dim3(VP, NC), 640, 0, stream>>>(x, Mpp, ebuf, n0);
    k_prop<<<dim3(4, 16, NC), 256, 0, stream>>>(Bcat, ebuf, conv_b, out, bns, n0);
  }
  k_bnapply<<<(26214400/4 + 255)/256, 256, 0, stream>>>(out, bns, gamma, beta, 26214400/4);
}